// Round 1
// baseline (5602.111 us; speedup 1.0000x reference)
//
#include <hip/hip_runtime.h>
#include <math.h>

#define ATTN_SCALE 0.07216878364870322f  // 192^-0.5

// ---------------- RMSNorm: one block per row ----------------
__global__ __launch_bounds__(256) void rms_kernel(
    const float* __restrict__ in, int ld_in,
    const float* __restrict__ w,
    float* __restrict__ out, int ld_out, int N)
{
    const int row = blockIdx.x;
    const int tid = threadIdx.x;
    const float* x = in + (size_t)row * ld_in;
    float ss = 0.f;
    for (int i = tid * 4; i < N; i += 1024) {
        float4 v = *(const float4*)(x + i);
        ss += v.x * v.x + v.y * v.y + v.z * v.z + v.w * v.w;
    }
    #pragma unroll
    for (int off = 32; off > 0; off >>= 1)
        ss += __shfl_down(ss, off);
    __shared__ float red[4];
    const int lane = tid & 63, wid = tid >> 6;
    if (lane == 0) red[wid] = ss;
    __syncthreads();
    const float tot = red[0] + red[1] + red[2] + red[3];
    const float rs = rsqrtf(tot / (float)N + 1e-6f);
    float* o = out + (size_t)row * ld_out;
    for (int i = tid * 4; i < N; i += 1024) {
        float4 v = *(const float4*)(x + i);
        float4 wv = *(const float4*)(w + i);
        float4 r;
        r.x = v.x * rs * wv.x;
        r.y = v.y * rs * wv.y;
        r.z = v.z * rs * wv.z;
        r.w = v.w * rs * wv.w;
        *(float4*)(o + i) = r;
    }
}

// ---------------- GEMM: C[M,N] = A[M,K]@B[K,N] (+R), row-major ----------------
// M assumed multiple of 128 (grid.y covers it); N guarded; K multiple of 8.
__global__ __launch_bounds__(256) void gemm_kernel(
    const float* __restrict__ A, int lda,
    const float* __restrict__ B, int ldb,
    float* __restrict__ C, int ldc,
    const float* __restrict__ R, int ldr,
    int N, int K)
{
    __shared__ float As[8][128];
    __shared__ float Bs[8][128];
    const int tid = threadIdx.x;
    const int row0 = blockIdx.y * 128;
    const int col0 = blockIdx.x * 128;
    const int tx = tid & 15;
    const int ty = tid >> 4;
    const int a_m = tid >> 1;
    const int a_k = (tid & 1) << 2;
    const int b_k = tid >> 5;
    const int b_c = (tid & 31) << 2;

    float acc[8][8];
    #pragma unroll
    for (int i = 0; i < 8; ++i)
        #pragma unroll
        for (int j = 0; j < 8; ++j) acc[i][j] = 0.f;

    const float* Ap = A + (size_t)(row0 + a_m) * lda + a_k;
    const float* Bp = B + (size_t)b_k * ldb + col0 + b_c;
    const bool bg = (col0 + 128 > N);
    const int nk = K >> 3;

    for (int kt = 0; kt < nk; ++kt) {
        float4 av = *(const float4*)Ap;
        float4 bv = make_float4(0.f, 0.f, 0.f, 0.f);
        if (!bg) {
            bv = *(const float4*)Bp;
        } else {
            int c = col0 + b_c;
            if (c + 0 < N) bv.x = Bp[0];
            if (c + 1 < N) bv.y = Bp[1];
            if (c + 2 < N) bv.z = Bp[2];
            if (c + 3 < N) bv.w = Bp[3];
        }
        As[a_k + 0][a_m] = av.x;
        As[a_k + 1][a_m] = av.y;
        As[a_k + 2][a_m] = av.z;
        As[a_k + 3][a_m] = av.w;
        *(float4*)&Bs[b_k][b_c] = bv;
        __syncthreads();
        #pragma unroll
        for (int kk = 0; kk < 8; ++kk) {
            float ar[8], br[8];
            *(float4*)&ar[0] = *(const float4*)&As[kk][ty << 2];
            *(float4*)&ar[4] = *(const float4*)&As[kk][64 + (ty << 2)];
            *(float4*)&br[0] = *(const float4*)&Bs[kk][tx << 2];
            *(float4*)&br[4] = *(const float4*)&Bs[kk][64 + (tx << 2)];
            #pragma unroll
            for (int i = 0; i < 8; ++i)
                #pragma unroll
                for (int j = 0; j < 8; ++j)
                    acc[i][j] = fmaf(ar[i], br[j], acc[i][j]);
        }
        __syncthreads();
        Ap += 8;
        Bp += (size_t)ldb * 8;
    }

    #pragma unroll
    for (int i = 0; i < 8; ++i) {
        int m = row0 + ((i < 4) ? ((ty << 2) + i) : (64 + (ty << 2) + (i - 4)));
        #pragma unroll
        for (int half = 0; half < 2; ++half) {
            int n = col0 + (half ? 64 : 0) + (tx << 2);
            float v[4];
            #pragma unroll
            for (int j = 0; j < 4; ++j) v[j] = acc[i][half * 4 + j];
            float* cp = C + (size_t)m * ldc + n;
            if (!bg) {
                if (R) {
                    float4 rv = *(const float4*)(R + (size_t)m * ldr + n);
                    v[0] += rv.x; v[1] += rv.y; v[2] += rv.z; v[3] += rv.w;
                }
                float4 o;
                o.x = v[0]; o.y = v[1]; o.z = v[2]; o.w = v[3];
                *(float4*)cp = o;
            } else {
                #pragma unroll
                for (int j = 0; j < 4; ++j) {
                    if (n + j < N) {
                        float val = v[j];
                        if (R) val += R[(size_t)m * ldr + n + j];
                        cp[j] = val;
                    }
                }
            }
        }
    }
}

// ---------------- RoPE (interleave -> half layout), in-place ----------------
// 32 threads per (row, head) group; groups aligned to blocks so the
// read-all-then-write-all is safe under one __syncthreads.
__global__ __launch_bounds__(256) void rope_kernel(
    float* __restrict__ x, int ld, int head_stride, int col_off, int n_heads,
    const float* __restrict__ cosb, const float* __restrict__ sinb,
    const int* __restrict__ pos_ids)
{
    const int gid = blockIdx.x * 256 + threadIdx.x;
    const int i = gid & 31;
    const int grp = gid >> 5;
    const int h = grp % n_heads;
    const int row = grp / n_heads;
    float* base = x + (size_t)row * ld + col_off + h * head_stride;
    const float x0 = base[2 * i];
    const float x1 = base[2 * i + 1];
    const int p = pos_ids[row];
    const float c = cosb[p * 64 + i];
    const float s = sinb[p * 64 + i];
    __syncthreads();
    base[i]      = x0 * c - x1 * s;
    base[32 + i] = x1 * c + x0 * s;
}

// ---------------- Flash attention (fp32), 64-row Q tile, KT=64 ----------------
// grid (16, NH): block bx handles qtiles {bx, 31-bx} (uniform work), 256 thr.
__global__ __launch_bounds__(256) void attn_kernel(
    const float* __restrict__ q,    // [2048, 3072] (pe part roped)
    const float* __restrict__ kv,   // [2048, 4096] (k_nope | v per head)
    const float* __restrict__ ckv,  // [2048, 576]  (cols 512.. roped k_pe)
    float* __restrict__ out)        // [2048, 2048]
{
    __shared__ float Qs[192][68];
    __shared__ float Ks[192][68];
    __shared__ float Vs[64][128];
    __shared__ float Ss[64][66];

    const int tid = threadIdx.x;
    const int h = blockIdx.y;
    const int r4  = (tid & 15) << 2;  // 4 q-rows
    const int kc4 = (tid >> 4) << 2;  // 4 k-cols (phase A)
    const int d0  = (tid >> 4) << 3;  // 8 v-dims (phase B)

    for (int pass = 0; pass < 2; ++pass) {
        const int qt = pass ? (31 - (int)blockIdx.x) : (int)blockIdx.x;
        const int q0 = qt << 6;

        for (int idx = tid; idx < 64 * 192; idx += 256) {
            int r = idx / 192, d = idx - r * 192;
            Qs[d][r] = q[(size_t)(q0 + r) * 3072 + h * 192 + d] * ATTN_SCALE;
        }

        float m_[4], l_[4], acc[4][8];
        #pragma unroll
        for (int a = 0; a < 4; ++a) {
            m_[a] = -1e30f; l_[a] = 0.f;
            #pragma unroll
            for (int j = 0; j < 8; ++j) acc[a][j] = 0.f;
        }

        const int nkt = qt + 1;
        for (int kt = 0; kt < nkt; ++kt) {
            const int k0 = kt << 6;
            for (int idx = tid; idx < 64 * 192; idx += 256) {
                int r = idx / 192, d = idx - r * 192;
                float val = (d < 128)
                    ? kv[(size_t)(k0 + r) * 4096 + h * 256 + d]
                    : ckv[(size_t)(k0 + r) * 576 + 512 + (d - 128)];
                Ks[d][r] = val;
            }
            for (int idx = tid; idx < 64 * 32; idx += 256) {
                int r = idx >> 5, dd = (idx & 31) << 2;
                *(float4*)&Vs[r][dd] =
                    *(const float4*)&kv[(size_t)(k0 + r) * 4096 + h * 256 + 128 + dd];
            }
            __syncthreads();

            // phase A: 4x4 scores per thread
            float s[4][4];
            #pragma unroll
            for (int a = 0; a < 4; ++a)
                #pragma unroll
                for (int b = 0; b < 4; ++b) s[a][b] = 0.f;
            for (int d = 0; d < 192; ++d) {
                float4 qv = *(const float4*)&Qs[d][r4];
                float4 kk = *(const float4*)&Ks[d][kc4];
                s[0][0] = fmaf(qv.x, kk.x, s[0][0]);
                s[0][1] = fmaf(qv.x, kk.y, s[0][1]);
                s[0][2] = fmaf(qv.x, kk.z, s[0][2]);
                s[0][3] = fmaf(qv.x, kk.w, s[0][3]);
                s[1][0] = fmaf(qv.y, kk.x, s[1][0]);
                s[1][1] = fmaf(qv.y, kk.y, s[1][1]);
                s[1][2] = fmaf(qv.y, kk.z, s[1][2]);
                s[1][3] = fmaf(qv.y, kk.w, s[1][3]);
                s[2][0] = fmaf(qv.z, kk.x, s[2][0]);
                s[2][1] = fmaf(qv.z, kk.y, s[2][1]);
                s[2][2] = fmaf(qv.z, kk.z, s[2][2]);
                s[2][3] = fmaf(qv.z, kk.w, s[2][3]);
                s[3][0] = fmaf(qv.w, kk.x, s[3][0]);
                s[3][1] = fmaf(qv.w, kk.y, s[3][1]);
                s[3][2] = fmaf(qv.w, kk.z, s[3][2]);
                s[3][3] = fmaf(qv.w, kk.w, s[3][3]);
            }
            #pragma unroll
            for (int a = 0; a < 4; ++a) {
                int qg = q0 + r4 + a;
                #pragma unroll
                for (int b = 0; b < 4; ++b) {
                    int kg = k0 + kc4 + b;
                    Ss[r4 + a][kc4 + b] = (kg <= qg) ? s[a][b] : -1e30f;
                }
            }
            __syncthreads();

            // phase B: online softmax + PV on 4 rows x 8 dims
            float mx[4] = {-1e30f, -1e30f, -1e30f, -1e30f};
            for (int k = 0; k < 64; k += 2) {
                #pragma unroll
                for (int a = 0; a < 4; ++a) {
                    float2 sv = *(const float2*)&Ss[r4 + a][k];
                    mx[a] = fmaxf(mx[a], fmaxf(sv.x, sv.y));
                }
            }
            #pragma unroll
            for (int a = 0; a < 4; ++a) {
                float mn = fmaxf(m_[a], mx[a]);
                float al = __expf(m_[a] - mn);
                m_[a] = mn;
                l_[a] *= al;
                #pragma unroll
                for (int j = 0; j < 8; ++j) acc[a][j] *= al;
            }
            for (int k = 0; k < 64; ++k) {
                float4 v0 = *(const float4*)&Vs[k][d0];
                float4 v1 = *(const float4*)&Vs[k][d0 + 4];
                #pragma unroll
                for (int a = 0; a < 4; ++a) {
                    float p = __expf(Ss[r4 + a][k] - m_[a]);
                    l_[a] += p;
                    acc[a][0] = fmaf(p, v0.x, acc[a][0]);
                    acc[a][1] = fmaf(p, v0.y, acc[a][1]);
                    acc[a][2] = fmaf(p, v0.z, acc[a][2]);
                    acc[a][3] = fmaf(p, v0.w, acc[a][3]);
                    acc[a][4] = fmaf(p, v1.x, acc[a][4]);
                    acc[a][5] = fmaf(p, v1.y, acc[a][5]);
                    acc[a][6] = fmaf(p, v1.z, acc[a][6]);
                    acc[a][7] = fmaf(p, v1.w, acc[a][7]);
                }
            }
            __syncthreads();
        }

        #pragma unroll
        for (int a = 0; a < 4; ++a) {
            float inv = 1.0f / l_[a];
            float4 o0, o1;
            o0.x = acc[a][0] * inv; o0.y = acc[a][1] * inv;
            o0.z = acc[a][2] * inv; o0.w = acc[a][3] * inv;
            o1.x = acc[a][4] * inv; o1.y = acc[a][5] * inv;
            o1.z = acc[a][6] * inv; o1.w = acc[a][7] * inv;
            float* op = out + (size_t)(q0 + r4 + a) * 2048 + h * 128 + d0;
            *(float4*)op = o0;
            *(float4*)(op + 4) = o1;
        }
    }
}

// ---------------- silu(g) * u, in place into g ----------------
__global__ __launch_bounds__(256) void silu_mul_kernel(
    float* __restrict__ g, const float* __restrict__ u, int n4)
{
    int i = blockIdx.x * 256 + threadIdx.x;
    if (i >= n4) return;
    float4 gv = ((const float4*)g)[i];
    float4 uv = ((const float4*)u)[i];
    float4 r;
    r.x = gv.x * uv.x / (1.f + __expf(-gv.x));
    r.y = gv.y * uv.y / (1.f + __expf(-gv.y));
    r.z = gv.z * uv.z / (1.f + __expf(-gv.z));
    r.w = gv.w * uv.w / (1.f + __expf(-gv.w));
    ((float4*)g)[i] = r;
}

extern "C" void kernel_launch(void* const* d_in, const int* in_sizes, int n_in,
                              void* d_out, int out_size, void* d_ws, size_t ws_size,
                              hipStream_t stream)
{
    (void)in_sizes; (void)n_in; (void)out_size; (void)ws_size;
    const float* hidden  = (const float*)d_in[0];
    const float* sinb    = (const float*)d_in[1];
    const float* cosb    = (const float*)d_in[2];
    const float* wq_a    = (const float*)d_in[3];
    const float* q_a_ln  = (const float*)d_in[4];
    const float* wq_b    = (const float*)d_in[5];
    const float* wkv_a   = (const float*)d_in[6];
    const float* kv_a_ln = (const float*)d_in[7];
    const float* wkv_b   = (const float*)d_in[8];
    const float* wo      = (const float*)d_in[9];
    const float* in_ln   = (const float*)d_in[10];
    const float* post_ln = (const float*)d_in[11];
    const float* w_gate  = (const float*)d_in[12];
    const float* w_up    = (const float*)d_in[13];
    const float* w_down  = (const float*)d_in[14];
    const int*   pos     = (const int*)d_in[15];

    float* ws  = (float*)d_ws;
    float* xn   = ws;                  // 2048x2048   (also reused as y later)
    float* q_a  = xn   + 4194304;      // 2048x1536
    float* qb   = q_a  + 3145728;      // 2048x3072
    float* ckv  = qb   + 6291456;      // 2048x576
    float* kvn  = ckv  + 1179648;      // 2048x512
    float* kvb  = kvn  + 1048576;      // 2048x4096
    float* att  = kvb  + 8388608;      // 2048x2048
    float* h2   = att  + 4194304;      // 2048x2048
    float* gbuf = h2   + 4194304;      // 2048x8192
    float* ubuf = gbuf + 16777216;     // 2048x8192
    float* outp = (float*)d_out;

    // x = rms(hidden, in_ln)
    rms_kernel<<<2048, 256, 0, stream>>>(hidden, 2048, in_ln, xn, 2048, 2048);
    // q_a = x @ wq_a ; rms in place
    gemm_kernel<<<dim3(12, 16), 256, 0, stream>>>(xn, 2048, wq_a, 1536, q_a, 1536, nullptr, 0, 1536, 2048);
    rms_kernel<<<2048, 256, 0, stream>>>(q_a, 1536, q_a_ln, q_a, 1536, 1536);
    // q = q_a @ wq_b
    gemm_kernel<<<dim3(24, 16), 256, 0, stream>>>(q_a, 1536, wq_b, 3072, qb, 3072, nullptr, 0, 3072, 1536);
    // ckv = x @ wkv_a  (N=576, guarded)
    gemm_kernel<<<dim3(5, 16), 256, 0, stream>>>(xn, 2048, wkv_a, 576, ckv, 576, nullptr, 0, 576, 2048);
    // kvn = rms(ckv[:, :512])
    rms_kernel<<<2048, 256, 0, stream>>>(ckv, 576, kv_a_ln, kvn, 512, 512);
    // kv = kvn @ wkv_b
    gemm_kernel<<<dim3(32, 16), 256, 0, stream>>>(kvn, 512, wkv_b, 4096, kvb, 4096, nullptr, 0, 4096, 512);
    // RoPE q_pe (16 heads) and k_pe (shared), in place
    rope_kernel<<<4096, 256, 0, stream>>>(qb, 3072, 192, 128, 16, cosb, sinb, pos);
    rope_kernel<<<256, 256, 0, stream>>>(ckv, 576, 0, 512, 1, cosb, sinb, pos);
    // attention
    attn_kernel<<<dim3(16, 16), 256, 0, stream>>>(qb, kvb, ckv, att);
    // h2 = att @ wo + hidden
    gemm_kernel<<<dim3(16, 16), 256, 0, stream>>>(att, 2048, wo, 2048, h2, 2048, hidden, 2048, 2048, 2048);
    // y = rms(h2, post_ln) -> reuse xn
    rms_kernel<<<2048, 256, 0, stream>>>(h2, 2048, post_ln, xn, 2048, 2048);
    // gate, up
    gemm_kernel<<<dim3(64, 16), 256, 0, stream>>>(xn, 2048, w_gate, 8192, gbuf, 8192, nullptr, 0, 8192, 2048);
    gemm_kernel<<<dim3(64, 16), 256, 0, stream>>>(xn, 2048, w_up, 8192, ubuf, 8192, nullptr, 0, 8192, 2048);
    // gbuf = silu(gbuf) * ubuf
    silu_mul_kernel<<<16384, 256, 0, stream>>>(gbuf, ubuf, 4194304);
    // out = gbuf @ w_down + h2
    gemm_kernel<<<dim3(16, 16), 256, 0, stream>>>(gbuf, 8192, w_down, 2048, outp, 2048, h2, 2048, 2048, 8192);
}

// Round 2
// 1891.166 us; speedup vs baseline: 2.9623x; 2.9623x over previous
//
#include <hip/hip_runtime.h>
#include <math.h>

#define ATTN_SCALE 0.07216878364870322f  // 192^-0.5

typedef __attribute__((ext_vector_type(8))) short short8;
typedef __attribute__((ext_vector_type(4))) float floatx4;

__device__ __forceinline__ unsigned short f2bf(float f) {
    union { float f; unsigned int u; } v; v.f = f;
    unsigned int r = v.u + 0x7fffu + ((v.u >> 16) & 1u);
    return (unsigned short)(r >> 16);
}
__device__ __forceinline__ float bf2f(unsigned short h) {
    union { unsigned int u; float f; } v; v.u = ((unsigned int)h) << 16;
    return v.f;
}
// async global->LDS, 16B per lane; HW dest = wave-uniform base + lane*16,
// we pass per-lane base+l*16 so lane0's value IS the wave base.
__device__ __forceinline__ void gld16(const void* g, void* l) {
    __builtin_amdgcn_global_load_lds(
        (const __attribute__((address_space(1))) unsigned int*)g,
        (__attribute__((address_space(3))) unsigned int*)l, 16, 0, 0);
}

// ---------------- RMSNorm fp32 in -> bf16 out ----------------
__global__ __launch_bounds__(256) void rms_kernel(
    const float* __restrict__ in, int ld_in,
    const float* __restrict__ w,
    unsigned short* __restrict__ out, int ld_out, int N)
{
    const int row = blockIdx.x;
    const int tid = threadIdx.x;
    const float* x = in + (size_t)row * ld_in;
    float ss = 0.f;
    for (int i = tid * 4; i < N; i += 1024) {
        float4 v = *(const float4*)(x + i);
        ss += v.x * v.x + v.y * v.y + v.z * v.z + v.w * v.w;
    }
    #pragma unroll
    for (int off = 32; off > 0; off >>= 1)
        ss += __shfl_down(ss, off);
    __shared__ float red[4];
    const int lane = tid & 63, wid = tid >> 6;
    if (lane == 0) red[wid] = ss;
    __syncthreads();
    const float tot = red[0] + red[1] + red[2] + red[3];
    const float rs = rsqrtf(tot / (float)N + 1e-6f);
    unsigned short* o = out + (size_t)row * ld_out;
    for (int i = tid * 4; i < N; i += 1024) {
        float4 v = *(const float4*)(x + i);
        float4 wv = *(const float4*)(w + i);
        __align__(8) unsigned short ov[4];
        ov[0] = f2bf(v.x * rs * wv.x);
        ov[1] = f2bf(v.y * rs * wv.y);
        ov[2] = f2bf(v.z * rs * wv.z);
        ov[3] = f2bf(v.w * rs * wv.w);
        *(uint2*)&o[i] = *(uint2*)ov;
    }
}

// ---------------- weight cast+transpose: W fp32[K,N] -> Wt bf16[Npad,K] ----------------
// grid (Npad/64, K/64); zero-fills rows n >= N.
__global__ __launch_bounds__(256) void cast_transpose_kernel(
    const float* __restrict__ W, unsigned short* __restrict__ Wt,
    int K, int N)
{
    __shared__ float tile[64][65];
    const int tid = threadIdx.x;
    const int kb = blockIdx.y * 64;
    const int nb = blockIdx.x * 64;
    const int r  = tid >> 2;
    const int c0 = (tid & 3) * 16;
    if (nb + 64 <= N) {
        #pragma unroll
        for (int j = 0; j < 16; j += 4)
            *(float4*)&tile[r][c0 + j] =
                *(const float4*)&W[(size_t)(kb + r) * N + nb + c0 + j];
    } else {
        for (int j = 0; j < 16; ++j) {
            int n = nb + c0 + j;
            tile[r][c0 + j] = (n < N) ? W[(size_t)(kb + r) * N + n] : 0.f;
        }
    }
    __syncthreads();
    __align__(16) unsigned short ov[16];
    #pragma unroll
    for (int j = 0; j < 16; ++j) ov[j] = f2bf(tile[c0 + j][r]);
    int4* dst = (int4*)&Wt[(size_t)(nb + r) * K + kb + c0];
    dst[0] = ((int4*)ov)[0];
    dst[1] = ((int4*)ov)[1];
}

// ---------------- bf16 MFMA GEMM: C[M,N] = A[M,K] @ Bt[N,K]^T (+R) ----------------
// 128x128 tile, 4 waves (2x2), each wave 4x4 of 16x16x32 MFMA, BK=32,
// global_load_lds staging in fragment-chunk order (conflict-free ds_read_b128).
// M multiple of 128 via grid.y; K multiple of 32; N guarded (Bt rows padded).
__global__ __launch_bounds__(256) void gemm_bf16_kernel(
    const unsigned short* __restrict__ A,   // [M,K] bf16
    const unsigned short* __restrict__ Bt,  // [Npad,K] bf16
    float* __restrict__ C,                  // fp32 out (or null)
    unsigned short* __restrict__ Cb,        // bf16 out (or null)
    const float* __restrict__ R,            // fp32 residual, ld=N (or null)
    int N, int K)
{
    __shared__ __align__(16) unsigned short As[4096];  // 8 groups x (4 kc x 16 m x 8)
    __shared__ __align__(16) unsigned short Bs[4096];
    const int tid = threadIdx.x;
    const int w  = tid >> 6;
    const int l  = tid & 63;
    const int lm = l & 15;
    const int lk = l >> 4;
    const int row0 = blockIdx.y * 128;
    const int col0 = blockIdx.x * 128;
    const int wm = (w >> 1) * 64;
    const int wn = (w & 1) * 64;

    const unsigned short* a0 = A  + (size_t)(row0 + w * 16 + lm) * K + lk * 8;
    const unsigned short* a1 = a0 + (size_t)64 * K;
    const unsigned short* b0 = Bt + (size_t)(col0 + w * 16 + lm) * K + lk * 8;
    const unsigned short* b1 = b0 + (size_t)64 * K;
    unsigned short* lA0 = As + w * 512 + l * 8;
    unsigned short* lA1 = As + (w + 4) * 512 + l * 8;
    unsigned short* lB0 = Bs + w * 512 + l * 8;
    unsigned short* lB1 = Bs + (w + 4) * 512 + l * 8;

    floatx4 acc[4][4];
    #pragma unroll
    for (int i = 0; i < 4; ++i)
        #pragma unroll
        for (int j = 0; j < 4; ++j)
            acc[i][j] = (floatx4){0.f, 0.f, 0.f, 0.f};

    for (int k0 = 0; k0 < K; k0 += 32) {
        gld16(a0, lA0);
        gld16(a1, lA1);
        gld16(b0, lB0);
        gld16(b1, lB1);
        a0 += 32; a1 += 32; b0 += 32; b1 += 32;
        __syncthreads();
        short8 af[4], bg_[4];
        #pragma unroll
        for (int i = 0; i < 4; ++i)
            af[i] = *(const short8*)&As[((w >> 1) * 4 + i) * 512 + l * 8];
        #pragma unroll
        for (int j = 0; j < 4; ++j)
            bg_[j] = *(const short8*)&Bs[((w & 1) * 4 + j) * 512 + l * 8];
        #pragma unroll
        for (int i = 0; i < 4; ++i)
            #pragma unroll
            for (int j = 0; j < 4; ++j)
                acc[i][j] = __builtin_amdgcn_mfma_f32_16x16x32_bf16(
                    af[i], bg_[j], acc[i][j], 0, 0, 0);
        __syncthreads();
    }

    const int quad = l >> 4;
    const bool ng = (col0 + 128 > N);
    #pragma unroll
    for (int i = 0; i < 4; ++i) {
        #pragma unroll
        for (int r = 0; r < 4; ++r) {
            const int m = row0 + wm + i * 16 + quad * 4 + r;
            #pragma unroll
            for (int j = 0; j < 4; ++j) {
                const int n = col0 + wn + j * 16 + lm;
                if (ng && n >= N) continue;
                const size_t off = (size_t)m * N + n;
                float v = acc[i][j][r];
                if (Cb) {
                    Cb[off] = f2bf(v);
                } else {
                    if (R) v += R[off];
                    C[off] = v;
                }
            }
        }
    }
}

// ---------------- RoPE (interleave -> half layout), in-place, fp32 ----------------
__global__ __launch_bounds__(256) void rope_kernel(
    float* __restrict__ x, int ld, int head_stride, int col_off, int n_heads,
    const float* __restrict__ cosb, const float* __restrict__ sinb,
    const int* __restrict__ pos_ids)
{
    const int gid = blockIdx.x * 256 + threadIdx.x;
    const int i = gid & 31;
    const int grp = gid >> 5;
    const int h = grp % n_heads;
    const int row = grp / n_heads;
    float* base = x + (size_t)row * ld + col_off + h * head_stride;
    const float x0 = base[2 * i];
    const float x1 = base[2 * i + 1];
    const int p = pos_ids[row];
    const float c = cosb[p * 64 + i];
    const float s = sinb[p * 64 + i];
    __syncthreads();
    base[i]      = x0 * c - x1 * s;
    base[32 + i] = x1 * c + x0 * s;
}

// ---------------- Flash attention (fp32 compute), bf16 output ----------------
__global__ __launch_bounds__(256) void attn_kernel(
    const float* __restrict__ q,    // [2048, 3072]
    const float* __restrict__ kv,   // [2048, 4096]
    const float* __restrict__ ckv,  // [2048, 576]
    unsigned short* __restrict__ out) // [2048, 2048] bf16
{
    __shared__ float Qs[192][68];
    __shared__ float Ks[192][68];
    __shared__ float Vs[64][128];
    __shared__ float Ss[64][66];

    const int tid = threadIdx.x;
    const int h = blockIdx.y;
    const int r4  = (tid & 15) << 2;
    const int kc4 = (tid >> 4) << 2;
    const int d0  = (tid >> 4) << 3;

    for (int pass = 0; pass < 2; ++pass) {
        const int qt = pass ? (31 - (int)blockIdx.x) : (int)blockIdx.x;
        const int q0 = qt << 6;

        for (int idx = tid; idx < 64 * 192; idx += 256) {
            int r = idx / 192, d = idx - r * 192;
            Qs[d][r] = q[(size_t)(q0 + r) * 3072 + h * 192 + d] * ATTN_SCALE;
        }

        float m_[4], l_[4], acc[4][8];
        #pragma unroll
        for (int a = 0; a < 4; ++a) {
            m_[a] = -1e30f; l_[a] = 0.f;
            #pragma unroll
            for (int j = 0; j < 8; ++j) acc[a][j] = 0.f;
        }

        const int nkt = qt + 1;
        for (int kt = 0; kt < nkt; ++kt) {
            const int k0 = kt << 6;
            for (int idx = tid; idx < 64 * 192; idx += 256) {
                int r = idx / 192, d = idx - r * 192;
                float val = (d < 128)
                    ? kv[(size_t)(k0 + r) * 4096 + h * 256 + d]
                    : ckv[(size_t)(k0 + r) * 576 + 512 + (d - 128)];
                Ks[d][r] = val;
            }
            for (int idx = tid; idx < 64 * 32; idx += 256) {
                int r = idx >> 5, dd = (idx & 31) << 2;
                *(float4*)&Vs[r][dd] =
                    *(const float4*)&kv[(size_t)(k0 + r) * 4096 + h * 256 + 128 + dd];
            }
            __syncthreads();

            float s[4][4];
            #pragma unroll
            for (int a = 0; a < 4; ++a)
                #pragma unroll
                for (int b = 0; b < 4; ++b) s[a][b] = 0.f;
            for (int d = 0; d < 192; ++d) {
                float4 qv = *(const float4*)&Qs[d][r4];
                float4 kk = *(const float4*)&Ks[d][kc4];
                s[0][0] = fmaf(qv.x, kk.x, s[0][0]);
                s[0][1] = fmaf(qv.x, kk.y, s[0][1]);
                s[0][2] = fmaf(qv.x, kk.z, s[0][2]);
                s[0][3] = fmaf(qv.x, kk.w, s[0][3]);
                s[1][0] = fmaf(qv.y, kk.x, s[1][0]);
                s[1][1] = fmaf(qv.y, kk.y, s[1][1]);
                s[1][2] = fmaf(qv.y, kk.z, s[1][2]);
                s[1][3] = fmaf(qv.y, kk.w, s[1][3]);
                s[2][0] = fmaf(qv.z, kk.x, s[2][0]);
                s[2][1] = fmaf(qv.z, kk.y, s[2][1]);
                s[2][2] = fmaf(qv.z, kk.z, s[2][2]);
                s[2][3] = fmaf(qv.z, kk.w, s[2][3]);
                s[3][0] = fmaf(qv.w, kk.x, s[3][0]);
                s[3][1] = fmaf(qv.w, kk.y, s[3][1]);
                s[3][2] = fmaf(qv.w, kk.z, s[3][2]);
                s[3][3] = fmaf(qv.w, kk.w, s[3][3]);
            }
            #pragma unroll
            for (int a = 0; a < 4; ++a) {
                int qg = q0 + r4 + a;
                #pragma unroll
                for (int b = 0; b < 4; ++b) {
                    int kg = k0 + kc4 + b;
                    Ss[r4 + a][kc4 + b] = (kg <= qg) ? s[a][b] : -1e30f;
                }
            }
            __syncthreads();

            float mx[4] = {-1e30f, -1e30f, -1e30f, -1e30f};
            for (int k = 0; k < 64; k += 2) {
                #pragma unroll
                for (int a = 0; a < 4; ++a) {
                    float2 sv = *(const float2*)&Ss[r4 + a][k];
                    mx[a] = fmaxf(mx[a], fmaxf(sv.x, sv.y));
                }
            }
            #pragma unroll
            for (int a = 0; a < 4; ++a) {
                float mn = fmaxf(m_[a], mx[a]);
                float al = __expf(m_[a] - mn);
                m_[a] = mn;
                l_[a] *= al;
                #pragma unroll
                for (int j = 0; j < 8; ++j) acc[a][j] *= al;
            }
            for (int k = 0; k < 64; ++k) {
                float4 v0 = *(const float4*)&Vs[k][d0];
                float4 v1 = *(const float4*)&Vs[k][d0 + 4];
                #pragma unroll
                for (int a = 0; a < 4; ++a) {
                    float p = __expf(Ss[r4 + a][k] - m_[a]);
                    l_[a] += p;
                    acc[a][0] = fmaf(p, v0.x, acc[a][0]);
                    acc[a][1] = fmaf(p, v0.y, acc[a][1]);
                    acc[a][2] = fmaf(p, v0.z, acc[a][2]);
                    acc[a][3] = fmaf(p, v0.w, acc[a][3]);
                    acc[a][4] = fmaf(p, v1.x, acc[a][4]);
                    acc[a][5] = fmaf(p, v1.y, acc[a][5]);
                    acc[a][6] = fmaf(p, v1.z, acc[a][6]);
                    acc[a][7] = fmaf(p, v1.w, acc[a][7]);
                }
            }
            __syncthreads();
        }

        #pragma unroll
        for (int a = 0; a < 4; ++a) {
            float inv = 1.0f / l_[a];
            __align__(16) unsigned short ov[8];
            #pragma unroll
            for (int j = 0; j < 8; ++j) ov[j] = f2bf(acc[a][j] * inv);
            *(int4*)(out + (size_t)(q0 + r4 + a) * 2048 + h * 128 + d0) = *(int4*)ov;
        }
    }
}

// ---------------- silu(g)*u, bf16 in/out, in place into g ----------------
__global__ __launch_bounds__(256) void silu_mul_kernel(
    unsigned short* __restrict__ g, const unsigned short* __restrict__ u, int n8)
{
    int i = blockIdx.x * 256 + threadIdx.x;
    if (i >= n8) return;
    int4 gv = ((const int4*)g)[i];
    int4 uv = ((const int4*)u)[i];
    const unsigned short* gs = (const unsigned short*)&gv;
    const unsigned short* us = (const unsigned short*)&uv;
    __align__(16) unsigned short ov[8];
    #pragma unroll
    for (int j = 0; j < 8; ++j) {
        float gf = bf2f(gs[j]), uf = bf2f(us[j]);
        ov[j] = f2bf(gf * uf / (1.f + __expf(-gf)));
    }
    ((int4*)g)[i] = *(int4*)ov;
}

extern "C" void kernel_launch(void* const* d_in, const int* in_sizes, int n_in,
                              void* d_out, int out_size, void* d_ws, size_t ws_size,
                              hipStream_t stream)
{
    (void)in_sizes; (void)n_in; (void)out_size; (void)ws_size;
    const float* hidden  = (const float*)d_in[0];
    const float* sinb    = (const float*)d_in[1];
    const float* cosb    = (const float*)d_in[2];
    const float* wq_a    = (const float*)d_in[3];
    const float* q_a_ln  = (const float*)d_in[4];
    const float* wq_b    = (const float*)d_in[5];
    const float* wkv_a   = (const float*)d_in[6];
    const float* kv_a_ln = (const float*)d_in[7];
    const float* wkv_b   = (const float*)d_in[8];
    const float* wo      = (const float*)d_in[9];
    const float* in_ln   = (const float*)d_in[10];
    const float* post_ln = (const float*)d_in[11];
    const float* w_gate  = (const float*)d_in[12];
    const float* w_up    = (const float*)d_in[13];
    const float* w_down  = (const float*)d_in[14];
    const int*   pos     = (const int*)d_in[15];

    char* wsb = (char*)d_ws;
    size_t used = 0;
    auto alloc = [&](size_t bytes) {
        char* p = wsb + used;
        used += (bytes + 255) & ~(size_t)255;
        return p;
    };
    float* q_a   = (float*)alloc((size_t)2048 * 1536 * 4);
    float* qb    = (float*)alloc((size_t)2048 * 3072 * 4);
    float* ckv   = (float*)alloc((size_t)2048 * 576 * 4);
    float* kvb   = (float*)alloc((size_t)2048 * 4096 * 4);
    float* h2    = (float*)alloc((size_t)2048 * 2048 * 4);
    unsigned short* xnb  = (unsigned short*)alloc((size_t)2048 * 2048 * 2);
    unsigned short* qab  = (unsigned short*)alloc((size_t)2048 * 1536 * 2);
    unsigned short* kvnb = (unsigned short*)alloc((size_t)2048 * 512 * 2);
    unsigned short* attb = (unsigned short*)alloc((size_t)2048 * 2048 * 2);
    unsigned short* gb   = (unsigned short*)alloc((size_t)2048 * 8192 * 2);
    unsigned short* ub   = (unsigned short*)alloc((size_t)2048 * 8192 * 2);
    unsigned short* wt   = (unsigned short*)alloc((size_t)16777216 * 2);
    float* outp = (float*)d_out;

    // x = rms(hidden) -> bf16
    rms_kernel<<<2048, 256, 0, stream>>>(hidden, 2048, in_ln, xnb, 2048, 2048);
    // q_a = x @ wq_a
    cast_transpose_kernel<<<dim3(24, 32), 256, 0, stream>>>(wq_a, wt, 2048, 1536);
    gemm_bf16_kernel<<<dim3(12, 16), 256, 0, stream>>>(xnb, wt, q_a, nullptr, nullptr, 1536, 2048);
    rms_kernel<<<2048, 256, 0, stream>>>(q_a, 1536, q_a_ln, qab, 1536, 1536);
    // q = q_a @ wq_b
    cast_transpose_kernel<<<dim3(48, 24), 256, 0, stream>>>(wq_b, wt, 1536, 3072);
    gemm_bf16_kernel<<<dim3(24, 16), 256, 0, stream>>>(qab, wt, qb, nullptr, nullptr, 3072, 1536);
    // ckv = x @ wkv_a (N=576, Bt padded to 640 rows)
    cast_transpose_kernel<<<dim3(10, 32), 256, 0, stream>>>(wkv_a, wt, 2048, 576);
    gemm_bf16_kernel<<<dim3(5, 16), 256, 0, stream>>>(xnb, wt, ckv, nullptr, nullptr, 576, 2048);
    // kvn = rms(ckv[:, :512]) -> bf16
    rms_kernel<<<2048, 256, 0, stream>>>(ckv, 576, kv_a_ln, kvnb, 512, 512);
    // kv = kvn @ wkv_b
    cast_transpose_kernel<<<dim3(64, 8), 256, 0, stream>>>(wkv_b, wt, 512, 4096);
    gemm_bf16_kernel<<<dim3(32, 16), 256, 0, stream>>>(kvnb, wt, kvb, nullptr, nullptr, 4096, 512);
    // RoPE
    rope_kernel<<<4096, 256, 0, stream>>>(qb, 3072, 192, 128, 16, cosb, sinb, pos);
    rope_kernel<<<256, 256, 0, stream>>>(ckv, 576, 0, 512, 1, cosb, sinb, pos);
    // attention -> bf16
    attn_kernel<<<dim3(16, 16), 256, 0, stream>>>(qb, kvb, ckv, attb);
    // h2 = att @ wo + hidden
    cast_transpose_kernel<<<dim3(32, 32), 256, 0, stream>>>(wo, wt, 2048, 2048);
    gemm_bf16_kernel<<<dim3(16, 16), 256, 0, stream>>>(attb, wt, h2, nullptr, hidden, 2048, 2048);
    // y = rms(h2) -> bf16 (reuse xnb)
    rms_kernel<<<2048, 256, 0, stream>>>(h2, 2048, post_ln, xnb, 2048, 2048);
    // gate, up (bf16 outputs)
    cast_transpose_kernel<<<dim3(128, 32), 256, 0, stream>>>(w_gate, wt, 2048, 8192);
    gemm_bf16_kernel<<<dim3(64, 16), 256, 0, stream>>>(xnb, wt, nullptr, gb, nullptr, 8192, 2048);
    cast_transpose_kernel<<<dim3(128, 32), 256, 0, stream>>>(w_up, wt, 2048, 8192);
    gemm_bf16_kernel<<<dim3(64, 16), 256, 0, stream>>>(xnb, wt, nullptr, ub, nullptr, 8192, 2048);
    // gb = silu(gb)*ub
    silu_mul_kernel<<<8192, 256, 0, stream>>>(gb, ub, 2097152);
    // out = gb @ w_down + h2
    cast_transpose_kernel<<<dim3(32, 128), 256, 0, stream>>>(w_down, wt, 8192, 2048);
    gemm_bf16_kernel<<<dim3(16, 16), 256, 0, stream>>>(gb, wt, outp, nullptr, h2, 2048, 8192);
}

// Round 3
// 1275.145 us; speedup vs baseline: 4.3933x; 1.4831x over previous
//
#include <hip/hip_runtime.h>
#include <math.h>

#define ATTN_SCALE 0.07216878364870322f  // 192^-0.5

typedef __attribute__((ext_vector_type(8))) short short8;
typedef __attribute__((ext_vector_type(4))) float floatx4;

__device__ __forceinline__ unsigned short f2bf(float f) {
    union { float f; unsigned int u; } v; v.f = f;
    unsigned int r = v.u + 0x7fffu + ((v.u >> 16) & 1u);
    return (unsigned short)(r >> 16);
}
__device__ __forceinline__ float bf2f(unsigned short h) {
    union { unsigned int u; float f; } v; v.u = ((unsigned int)h) << 16;
    return v.f;
}
__device__ __forceinline__ void gld16(const void* g, void* l) {
    __builtin_amdgcn_global_load_lds(
        (const __attribute__((address_space(1))) unsigned int*)g,
        (__attribute__((address_space(3))) unsigned int*)l, 16, 0, 0);
}

// ---------------- RMSNorm fp32 in -> bf16 out ----------------
__global__ __launch_bounds__(256) void rms_kernel(
    const float* __restrict__ in, int ld_in,
    const float* __restrict__ w,
    unsigned short* __restrict__ out, int ld_out, int N)
{
    const int row = blockIdx.x;
    const int tid = threadIdx.x;
    const float* x = in + (size_t)row * ld_in;
    float ss = 0.f;
    for (int i = tid * 4; i < N; i += 1024) {
        float4 v = *(const float4*)(x + i);
        ss += v.x * v.x + v.y * v.y + v.z * v.z + v.w * v.w;
    }
    #pragma unroll
    for (int off = 32; off > 0; off >>= 1)
        ss += __shfl_down(ss, off);
    __shared__ float red[4];
    const int lane = tid & 63, wid = tid >> 6;
    if (lane == 0) red[wid] = ss;
    __syncthreads();
    const float tot = red[0] + red[1] + red[2] + red[3];
    const float rs = rsqrtf(tot / (float)N + 1e-6f);
    unsigned short* o = out + (size_t)row * ld_out;
    for (int i = tid * 4; i < N; i += 1024) {
        float4 v = *(const float4*)(x + i);
        float4 wv = *(const float4*)(w + i);
        __align__(8) unsigned short ov[4];
        ov[0] = f2bf(v.x * rs * wv.x);
        ov[1] = f2bf(v.y * rs * wv.y);
        ov[2] = f2bf(v.z * rs * wv.z);
        ov[3] = f2bf(v.w * rs * wv.w);
        *(uint2*)&o[i] = *(uint2*)ov;
    }
}

// ---------------- weight cast+transpose: W fp32[K,N] -> Wt bf16[Npad,K] ----------------
__global__ __launch_bounds__(256) void cast_transpose_kernel(
    const float* __restrict__ W, unsigned short* __restrict__ Wt,
    int K, int N)
{
    __shared__ float tile[64][65];
    const int tid = threadIdx.x;
    const int kb = blockIdx.y * 64;
    const int nb = blockIdx.x * 64;
    const int r  = tid >> 2;
    const int c0 = (tid & 3) * 16;
    if (nb + 64 <= N) {
        #pragma unroll
        for (int j = 0; j < 16; j += 4)
            *(float4*)&tile[r][c0 + j] =
                *(const float4*)&W[(size_t)(kb + r) * N + nb + c0 + j];
    } else {
        for (int j = 0; j < 16; ++j) {
            int n = nb + c0 + j;
            tile[r][c0 + j] = (n < N) ? W[(size_t)(kb + r) * N + n] : 0.f;
        }
    }
    __syncthreads();
    __align__(16) unsigned short ov[16];
    #pragma unroll
    for (int j = 0; j < 16; ++j) ov[j] = f2bf(tile[c0 + j][r]);
    int4* dst = (int4*)&Wt[(size_t)(nb + r) * K + kb + c0];
    dst[0] = ((int4*)ov)[0];
    dst[1] = ((int4*)ov)[1];
}

// ---------------- bf16 MFMA GEMM (m97 structure) ----------------
__global__ __launch_bounds__(256) void gemm_bf16_kernel(
    const unsigned short* __restrict__ A,   // [M,K] bf16
    const unsigned short* __restrict__ Bt,  // [Npad,K] bf16
    float* __restrict__ C,                  // fp32 out (or null)
    unsigned short* __restrict__ Cb,        // bf16 out (or null)
    const float* __restrict__ R,            // fp32 residual (or null)
    int N, int K)
{
    __shared__ __align__(16) unsigned short As[4096];
    __shared__ __align__(16) unsigned short Bs[4096];
    const int tid = threadIdx.x;
    const int w  = tid >> 6;
    const int l  = tid & 63;
    const int lm = l & 15;
    const int lk = l >> 4;
    const int row0 = blockIdx.y * 128;
    const int col0 = blockIdx.x * 128;
    const int wm = (w >> 1) * 64;
    const int wn = (w & 1) * 64;

    const unsigned short* a0 = A  + (size_t)(row0 + w * 16 + lm) * K + lk * 8;
    const unsigned short* a1 = a0 + (size_t)64 * K;
    const unsigned short* b0 = Bt + (size_t)(col0 + w * 16 + lm) * K + lk * 8;
    const unsigned short* b1 = b0 + (size_t)64 * K;
    unsigned short* lA0 = As + w * 512 + l * 8;
    unsigned short* lA1 = As + (w + 4) * 512 + l * 8;
    unsigned short* lB0 = Bs + w * 512 + l * 8;
    unsigned short* lB1 = Bs + (w + 4) * 512 + l * 8;

    floatx4 acc[4][4];
    #pragma unroll
    for (int i = 0; i < 4; ++i)
        #pragma unroll
        for (int j = 0; j < 4; ++j)
            acc[i][j] = (floatx4){0.f, 0.f, 0.f, 0.f};

    for (int k0 = 0; k0 < K; k0 += 32) {
        gld16(a0, lA0);
        gld16(a1, lA1);
        gld16(b0, lB0);
        gld16(b1, lB1);
        a0 += 32; a1 += 32; b0 += 32; b1 += 32;
        __syncthreads();
        short8 af[4], bg_[4];
        #pragma unroll
        for (int i = 0; i < 4; ++i)
            af[i] = *(const short8*)&As[((w >> 1) * 4 + i) * 512 + l * 8];
        #pragma unroll
        for (int j = 0; j < 4; ++j)
            bg_[j] = *(const short8*)&Bs[((w & 1) * 4 + j) * 512 + l * 8];
        #pragma unroll
        for (int i = 0; i < 4; ++i)
            #pragma unroll
            for (int j = 0; j < 4; ++j)
                acc[i][j] = __builtin_amdgcn_mfma_f32_16x16x32_bf16(
                    af[i], bg_[j], acc[i][j], 0, 0, 0);
        __syncthreads();
    }

    const int quad = l >> 4;
    const bool ng = (col0 + 128 > N);
    #pragma unroll
    for (int i = 0; i < 4; ++i) {
        #pragma unroll
        for (int r = 0; r < 4; ++r) {
            const int m = row0 + wm + i * 16 + quad * 4 + r;
            #pragma unroll
            for (int j = 0; j < 4; ++j) {
                const int n = col0 + wn + j * 16 + lm;
                if (ng && n >= N) continue;
                const size_t off = (size_t)m * N + n;
                float v = acc[i][j][r];
                if (Cb) {
                    Cb[off] = f2bf(v);
                } else {
                    if (R) v += R[off];
                    C[off] = v;
                }
            }
        }
    }
}

// ---------------- RoPE on bf16 q (in place, interleave -> half) ----------------
__global__ __launch_bounds__(256) void rope_q_kernel(
    unsigned short* __restrict__ x,
    const float* __restrict__ cosb, const float* __restrict__ sinb,
    const int* __restrict__ pos_ids)
{
    const int gid = blockIdx.x * 256 + threadIdx.x;
    const int i = gid & 31;
    const int grp = gid >> 5;
    const int hh = grp & 15;
    const int row = grp >> 4;
    unsigned short* base = x + (size_t)row * 3072 + hh * 192 + 128;
    const float x0 = bf2f(base[2 * i]);
    const float x1 = bf2f(base[2 * i + 1]);
    const int p = pos_ids[row];
    const float c = cosb[p * 64 + i];
    const float s = sinb[p * 64 + i];
    __syncthreads();
    base[i]      = f2bf(x0 * c - x1 * s);
    base[32 + i] = f2bf(x1 * c + x0 * s);
}

// ---------------- RoPE k_pe: ckv fp32 cols 512.. -> kpe bf16 [2048][64] ----------------
__global__ __launch_bounds__(256) void rope_kpe_kernel(
    const float* __restrict__ ckv, unsigned short* __restrict__ kpe,
    const float* __restrict__ cosb, const float* __restrict__ sinb,
    const int* __restrict__ pos_ids)
{
    const int gid = blockIdx.x * 256 + threadIdx.x;
    const int i = gid & 31;
    const int row = gid >> 5;
    const float x0 = ckv[(size_t)row * 576 + 512 + 2 * i];
    const float x1 = ckv[(size_t)row * 576 + 512 + 2 * i + 1];
    const int p = pos_ids[row];
    const float c = cosb[p * 64 + i];
    const float s = sinb[p * 64 + i];
    kpe[(size_t)row * 64 + i]      = f2bf(x0 * c - x1 * s);
    kpe[(size_t)row * 64 + 32 + i] = f2bf(x1 * c + x0 * s);
}

// ---------------- V transpose: kvb bf16 -> vtg[16][128][2048] bf16 ----------------
__global__ __launch_bounds__(256) void vtrans_kernel(
    const unsigned short* __restrict__ kvb, unsigned short* __restrict__ vtg)
{
    __shared__ unsigned short tile[64][72];
    const int tid = threadIdx.x;
    const int s0 = blockIdx.x * 64;
    const int d0 = blockIdx.y * 64;
    const int h  = blockIdx.z;
    const int r  = tid >> 2;
    const int c0 = (tid & 3) * 16;
    *(int4*)&tile[r][c0] =
        *(const int4*)&kvb[(size_t)(s0 + r) * 4096 + h * 256 + 128 + d0 + c0];
    *(int4*)&tile[r][c0 + 8] =
        *(const int4*)&kvb[(size_t)(s0 + r) * 4096 + h * 256 + 128 + d0 + c0 + 8];
    __syncthreads();
    __align__(16) unsigned short ov[16];
    #pragma unroll
    for (int j = 0; j < 16; ++j) ov[j] = tile[c0 + j][r];
    unsigned short* dst = vtg + ((size_t)(h * 128 + d0 + r)) * 2048 + s0 + c0;
    ((int4*)dst)[0] = ((int4*)ov)[0];
    ((int4*)dst)[1] = ((int4*)ov)[1];
}

// ---------------- MFMA flash attention ----------------
// grid (16, 16): block bx does qtiles {bx, 31-bx} (uniform). 512 threads.
// S^T = K·Q^T (C-layout reg axis = kpos), P packed b64 -> Ps[q][kpos],
// PV: O = P·V^T with A=Ps rows, B=Vt rows; Vt double-buffered + prefetch.
__global__ __launch_bounds__(512) void attn_mfma_kernel(
    const unsigned short* __restrict__ qb,   // [2048][3072] bf16 (roped)
    const unsigned short* __restrict__ kvb,  // [2048][4096] bf16
    const unsigned short* __restrict__ kpe,  // [2048][64] bf16 (roped)
    const unsigned short* __restrict__ vtg,  // [16][128][2048] bf16
    unsigned short* __restrict__ out)        // [2048][2048] bf16
{
    __shared__ __align__(16) unsigned short Kf[128 * 200];   // 51200 B, row stride 400 B
    __shared__ __align__(16) unsigned short Vt[2][128 * 136];// 2x34816 B, row stride 272 B
    __shared__ __align__(16) unsigned short Ps[64 * 136];    // 17408 B
    __shared__ float pmax_s[8][64];
    __shared__ float psum_s[8][64];
    __shared__ __align__(16) float m_state[64];
    __shared__ __align__(16) float l_state[64];
    __shared__ __align__(16) float alpha_s[64];
    __shared__ __align__(16) float mnew_s[64];

    const int tid  = threadIdx.x;
    const int w    = tid >> 6;
    const int l    = tid & 63;
    const int l15  = l & 15;
    const int quad = l >> 4;
    const int h    = blockIdx.y;
    const int qs   = (w & 3) * 16;   // PV q strip
    const int dh   = (w >> 2) * 64;  // PV d half

    for (int pass = 0; pass < 2; ++pass) {
        const int qt = pass ? (31 - (int)blockIdx.x) : (int)blockIdx.x;
        const int q0 = qt * 64;
        const int ntiles = (qt >> 1) + 1;

        // Q fragments in registers: qf[nt][c] = Q[q0+nt*16+l15][h*192 + c*32 + quad*8 ..]
        short8 qf[4][6];
        #pragma unroll
        for (int nt = 0; nt < 4; ++nt)
            #pragma unroll
            for (int c = 0; c < 6; ++c)
                qf[nt][c] = *(const short8*)&qb[(size_t)(q0 + nt * 16 + l15) * 3072
                                               + h * 192 + c * 32 + quad * 8];

        floatx4 oacc[4];
        #pragma unroll
        for (int nt = 0; nt < 4; ++nt) oacc[nt] = (floatx4){0.f, 0.f, 0.f, 0.f};
        if (tid < 64) { m_state[tid] = -3e38f; l_state[tid] = 0.f; }

        // stage tile 0
        {
            const int k0 = 0;
            for (int s = w; s < 50; s += 8) {
                unsigned ab = s * 1024 + l * 16;
                unsigned row = ab / 400u;
                unsigned g = (ab - row * 400u) >> 4;
                const unsigned short* src;
                if (g < 16u)      src = kvb + (size_t)(k0 + row) * 4096 + h * 256 + g * 8;
                else if (g < 24u) src = kpe + (size_t)(k0 + row) * 64 + (g - 16u) * 8;
                else              src = kpe + (size_t)(k0 + row) * 64;
                gld16(src, (char*)Kf + ab);
            }
            for (int s = w; s < 34; s += 8) {
                unsigned ab = s * 1024 + l * 16;
                unsigned row = ab / 272u;
                unsigned g = (ab - row * 272u) >> 4;
                const unsigned short* src =
                    vtg + (size_t)(h * 128 + row) * 2048 + k0 + (g < 16u ? g * 8 : 0u);
                gld16(src, (char*)Vt[0] + ab);
            }
        }

        for (int kt = 0; kt < ntiles; ++kt) {
            const int k0 = kt * 128;
            const int vb = kt & 1;
            __syncthreads();  // staging of kt complete; prev-iter LDS reads done

            // ---- QK^T: wave strip kpos = w*16 ----
            floatx4 st[4];
            #pragma unroll
            for (int nt = 0; nt < 4; ++nt) st[nt] = (floatx4){0.f, 0.f, 0.f, 0.f};
            #pragma unroll
            for (int c = 0; c < 6; ++c) {
                short8 kf = *(const short8*)&Kf[(w * 16 + l15) * 200 + c * 32 + quad * 8];
                #pragma unroll
                for (int nt = 0; nt < 4; ++nt)
                    st[nt] = __builtin_amdgcn_mfma_f32_16x16x32_bf16(kf, qf[nt][c], st[nt], 0, 0, 0);
            }
            // scale + causal mask + wave-local col max
            #pragma unroll
            for (int nt = 0; nt < 4; ++nt) {
                const int qq = q0 + nt * 16 + l15;
                float vmax = -3e38f;
                #pragma unroll
                for (int r = 0; r < 4; ++r) {
                    const int kpos = k0 + w * 16 + quad * 4 + r;
                    float v = st[nt][r] * ATTN_SCALE;
                    if (kpos > qq) v = -3e38f;
                    st[nt][r] = v;
                    vmax = fmaxf(vmax, v);
                }
                vmax = fmaxf(vmax, __shfl_xor(vmax, 16));
                vmax = fmaxf(vmax, __shfl_xor(vmax, 32));
                if (quad == 0) pmax_s[w][nt * 16 + l15] = vmax;
            }
            __syncthreads();  // pmax ready
            if (tid < 64) {
                float mp = m_state[tid];
                float mn = mp;
                #pragma unroll
                for (int ww = 0; ww < 8; ++ww) mn = fmaxf(mn, pmax_s[ww][tid]);
                alpha_s[tid] = __expf(mp - mn);
                mnew_s[tid] = mn;
                m_state[tid] = mn;
            }
            __syncthreads();  // mnew/alpha ready

            // ---- p = exp(s - m), pack -> Ps, col sums ----
            #pragma unroll
            for (int nt = 0; nt < 4; ++nt) {
                const float mn = mnew_s[nt * 16 + l15];
                float vsum = 0.f;
                __align__(8) unsigned short pb[4];
                #pragma unroll
                for (int r = 0; r < 4; ++r) {
                    float p = __expf(st[nt][r] - mn);
                    vsum += p;
                    pb[r] = f2bf(p);
                }
                *(uint2*)&Ps[(nt * 16 + l15) * 136 + w * 16 + quad * 4] = *(uint2*)pb;
                vsum += __shfl_xor(vsum, 16);
                vsum += __shfl_xor(vsum, 32);
                if (quad == 0) psum_s[w][nt * 16 + l15] = vsum;
            }
            // rescale O by alpha (rows q = qs + quad*4 + r)
            {
                float4 al4 = *(const float4*)&alpha_s[qs + quad * 4];
                #pragma unroll
                for (int nt = 0; nt < 4; ++nt) {
                    oacc[nt][0] *= al4.x; oacc[nt][1] *= al4.y;
                    oacc[nt][2] *= al4.z; oacc[nt][3] *= al4.w;
                }
            }
            __syncthreads();  // Ps + psum ready
            if (tid < 64) {
                float acc = 0.f;
                #pragma unroll
                for (int ww = 0; ww < 8; ++ww) acc += psum_s[ww][tid];
                l_state[tid] = l_state[tid] * alpha_s[tid] + acc;
            }
            // prefetch kt+1 (Kf reads done; Vt[!vb] free)
            if (kt + 1 < ntiles) {
                const int k1 = k0 + 128;
                for (int s = w; s < 50; s += 8) {
                    unsigned ab = s * 1024 + l * 16;
                    unsigned row = ab / 400u;
                    unsigned g = (ab - row * 400u) >> 4;
                    const unsigned short* src;
                    if (g < 16u)      src = kvb + (size_t)(k1 + row) * 4096 + h * 256 + g * 8;
                    else if (g < 24u) src = kpe + (size_t)(k1 + row) * 64 + (g - 16u) * 8;
                    else              src = kpe + (size_t)(k1 + row) * 64;
                    gld16(src, (char*)Kf + ab);
                }
                for (int s = w; s < 34; s += 8) {
                    unsigned ab = s * 1024 + l * 16;
                    unsigned row = ab / 272u;
                    unsigned g = (ab - row * 272u) >> 4;
                    const unsigned short* src =
                        vtg + (size_t)(h * 128 + row) * 2048 + k1 + (g < 16u ? g * 8 : 0u);
                    gld16(src, (char*)Vt[vb ^ 1] + ab);
                }
            }
            // ---- PV: O[qs strip][dh half] += P · V ----
            #pragma unroll
            for (int c = 0; c < 4; ++c) {
                short8 pf = *(const short8*)&Ps[(qs + l15) * 136 + c * 32 + quad * 8];
                #pragma unroll
                for (int nt = 0; nt < 4; ++nt) {
                    short8 vf = *(const short8*)&Vt[vb][(dh + nt * 16 + l15) * 136
                                                       + c * 32 + quad * 8];
                    oacc[nt] = __builtin_amdgcn_mfma_f32_16x16x32_bf16(pf, vf, oacc[nt], 0, 0, 0);
                }
            }
        }
        __syncthreads();  // l_state final; all LDS traffic done

        // ---- epilogue: O / l -> bf16 out ----
        {
            float4 l4 = *(const float4*)&l_state[qs + quad * 4];
            float inv0 = 1.f / l4.x, inv1 = 1.f / l4.y, inv2 = 1.f / l4.z, inv3 = 1.f / l4.w;
            #pragma unroll
            for (int nt = 0; nt < 4; ++nt) {
                const size_t col = h * 128 + dh + nt * 16 + l15;
                out[(size_t)(q0 + qs + quad * 4 + 0) * 2048 + col] = f2bf(oacc[nt][0] * inv0);
                out[(size_t)(q0 + qs + quad * 4 + 1) * 2048 + col] = f2bf(oacc[nt][1] * inv1);
                out[(size_t)(q0 + qs + quad * 4 + 2) * 2048 + col] = f2bf(oacc[nt][2] * inv2);
                out[(size_t)(q0 + qs + quad * 4 + 3) * 2048 + col] = f2bf(oacc[nt][3] * inv3);
            }
        }
        __syncthreads();  // protect m/l re-init of next pass
    }
}

// ---------------- silu(g)*u, bf16, in place into g ----------------
__global__ __launch_bounds__(256) void silu_mul_kernel(
    unsigned short* __restrict__ g, const unsigned short* __restrict__ u, int n8)
{
    int i = blockIdx.x * 256 + threadIdx.x;
    if (i >= n8) return;
    int4 gv = ((const int4*)g)[i];
    int4 uv = ((const int4*)u)[i];
    const unsigned short* gs = (const unsigned short*)&gv;
    const unsigned short* us = (const unsigned short*)&uv;
    __align__(16) unsigned short ov[8];
    #pragma unroll
    for (int j = 0; j < 8; ++j) {
        float gf = bf2f(gs[j]), uf = bf2f(us[j]);
        ov[j] = f2bf(gf * uf / (1.f + __expf(-gf)));
    }
    ((int4*)g)[i] = *(int4*)ov;
}

extern "C" void kernel_launch(void* const* d_in, const int* in_sizes, int n_in,
                              void* d_out, int out_size, void* d_ws, size_t ws_size,
                              hipStream_t stream)
{
    (void)in_sizes; (void)n_in; (void)out_size; (void)ws_size;
    const float* hidden  = (const float*)d_in[0];
    const float* sinb    = (const float*)d_in[1];
    const float* cosb    = (const float*)d_in[2];
    const float* wq_a    = (const float*)d_in[3];
    const float* q_a_ln  = (const float*)d_in[4];
    const float* wq_b    = (const float*)d_in[5];
    const float* wkv_a   = (const float*)d_in[6];
    const float* kv_a_ln = (const float*)d_in[7];
    const float* wkv_b   = (const float*)d_in[8];
    const float* wo      = (const float*)d_in[9];
    const float* in_ln   = (const float*)d_in[10];
    const float* post_ln = (const float*)d_in[11];
    const float* w_gate  = (const float*)d_in[12];
    const float* w_up    = (const float*)d_in[13];
    const float* w_down  = (const float*)d_in[14];
    const int*   pos     = (const int*)d_in[15];

    char* wsb = (char*)d_ws;
    size_t used = 0;
    auto alloc = [&](size_t bytes) {
        char* p = wsb + used;
        used += (bytes + 255) & ~(size_t)255;
        return p;
    };
    float* q_a   = (float*)alloc((size_t)2048 * 1536 * 4);
    float* ckv   = (float*)alloc((size_t)2048 * 576 * 4);
    float* h2    = (float*)alloc((size_t)2048 * 2048 * 4);
    unsigned short* xnb  = (unsigned short*)alloc((size_t)2048 * 2048 * 2);
    unsigned short* qab  = (unsigned short*)alloc((size_t)2048 * 1536 * 2);
    unsigned short* kvnb = (unsigned short*)alloc((size_t)2048 * 512 * 2);
    unsigned short* qbb  = (unsigned short*)alloc((size_t)2048 * 3072 * 2);
    unsigned short* kvbb = (unsigned short*)alloc((size_t)2048 * 4096 * 2);
    unsigned short* kpe  = (unsigned short*)alloc((size_t)2048 * 64 * 2);
    unsigned short* vtg  = (unsigned short*)alloc((size_t)16 * 128 * 2048 * 2);
    unsigned short* attb = (unsigned short*)alloc((size_t)2048 * 2048 * 2);
    unsigned short* gb   = (unsigned short*)alloc((size_t)2048 * 8192 * 2);
    unsigned short* ub   = (unsigned short*)alloc((size_t)2048 * 8192 * 2);
    unsigned short* wt   = (unsigned short*)alloc((size_t)16777216 * 2);
    float* outp = (float*)d_out;

    // x = rms(hidden) -> bf16
    rms_kernel<<<2048, 256, 0, stream>>>(hidden, 2048, in_ln, xnb, 2048, 2048);
    // q_a = x @ wq_a (fp32 out for rms)
    cast_transpose_kernel<<<dim3(24, 32), 256, 0, stream>>>(wq_a, wt, 2048, 1536);
    gemm_bf16_kernel<<<dim3(12, 16), 256, 0, stream>>>(xnb, wt, q_a, nullptr, nullptr, 1536, 2048);
    rms_kernel<<<2048, 256, 0, stream>>>(q_a, 1536, q_a_ln, qab, 1536, 1536);
    // q = q_a @ wq_b -> bf16
    cast_transpose_kernel<<<dim3(48, 24), 256, 0, stream>>>(wq_b, wt, 1536, 3072);
    gemm_bf16_kernel<<<dim3(24, 16), 256, 0, stream>>>(qab, wt, nullptr, qbb, nullptr, 3072, 1536);
    // ckv = x @ wkv_a (fp32, N=576)
    cast_transpose_kernel<<<dim3(10, 32), 256, 0, stream>>>(wkv_a, wt, 2048, 576);
    gemm_bf16_kernel<<<dim3(5, 16), 256, 0, stream>>>(xnb, wt, ckv, nullptr, nullptr, 576, 2048);
    // kvn = rms(ckv[:, :512]) -> bf16
    rms_kernel<<<2048, 256, 0, stream>>>(ckv, 576, kv_a_ln, kvnb, 512, 512);
    // kv = kvn @ wkv_b -> bf16
    cast_transpose_kernel<<<dim3(64, 8), 256, 0, stream>>>(wkv_b, wt, 512, 4096);
    gemm_bf16_kernel<<<dim3(32, 16), 256, 0, stream>>>(kvnb, wt, nullptr, kvbb, nullptr, 4096, 512);
    // RoPE
    rope_q_kernel<<<4096, 256, 0, stream>>>(qbb, cosb, sinb, pos);
    rope_kpe_kernel<<<256, 256, 0, stream>>>(ckv, kpe, cosb, sinb, pos);
    // V transpose
    vtrans_kernel<<<dim3(32, 2, 16), 256, 0, stream>>>(kvbb, vtg);
    // attention -> bf16
    attn_mfma_kernel<<<dim3(16, 16), 512, 0, stream>>>(qbb, kvbb, kpe, vtg, attb);
    // h2 = att @ wo + hidden (fp32)
    cast_transpose_kernel<<<dim3(32, 32), 256, 0, stream>>>(wo, wt, 2048, 2048);
    gemm_bf16_kernel<<<dim3(16, 16), 256, 0, stream>>>(attb, wt, h2, nullptr, hidden, 2048, 2048);
    // y = rms(h2) -> bf16
    rms_kernel<<<2048, 256, 0, stream>>>(h2, 2048, post_ln, xnb, 2048, 2048);
    // gate, up -> bf16
    cast_transpose_kernel<<<dim3(128, 32), 256, 0, stream>>>(w_gate, wt, 2048, 8192);
    gemm_bf16_kernel<<<dim3(64, 16), 256, 0, stream>>>(xnb, wt, nullptr, gb, nullptr, 8192, 2048);
    cast_transpose_kernel<<<dim3(128, 32), 256, 0, stream>>>(w_up, wt, 2048, 8192);
    gemm_bf16_kernel<<<dim3(64, 16), 256, 0, stream>>>(xnb, wt, nullptr, ub, nullptr, 8192, 2048);
    // gb = silu(gb)*ub
    silu_mul_kernel<<<8192, 256, 0, stream>>>(gb, ub, 2097152);
    // out = gb @ w_down + h2
    cast_transpose_kernel<<<dim3(32, 128), 256, 0, stream>>>(w_down, wt, 8192, 2048);
    gemm_bf16_kernel<<<dim3(16, 16), 256, 0, stream>>>(gb, wt, outp, nullptr, h2, 2048, 8192);
}